// Round 1
// baseline (211.343 us; speedup 1.0000x reference)
//
#include <hip/hip_runtime.h>
#include <math.h>

// DecodeSBP: x[1,133,512,512] fp32 -> per-keypoint argmax of sigmoid heatmap,
// conf-thresholded joints [133,3] = (x*4, y*4, conf) or (-4,-4,-1).

#define KPTS     133
#define WW       512
#define HW       (512 * 512)        // 262144 elements per keypoint row
#define NCHUNK   16                 // chunks per row (phase-1 blocks per row)
#define CHUNK    (HW / NCHUNK)      // 16384 elements
#define NTHREADS 256
#define V4_PER_T (CHUNK / 4 / NTHREADS)  // 16 float4 loads per thread

// (val, idx) argmax with first-index tie-break (matches jnp.argmax).
__device__ __forceinline__ void red(float& bv, unsigned& bi, float v, unsigned i) {
    if (v > bv || (v == bv && i < bi)) { bv = v; bi = i; }
}

__global__ __launch_bounds__(NTHREADS)
void k_phase1(const float* __restrict__ x,
              float* __restrict__ pv, unsigned* __restrict__ pi) {
    const int b = blockIdx.x;
    const int k = b / NCHUNK;          // keypoint row
    const int c = b % NCHUNK;          // chunk within row
    const int t = threadIdx.x;

    const float4* src = reinterpret_cast<const float4*>(
        x + (size_t)k * HW + (size_t)c * CHUNK);
    const unsigned base = (unsigned)(c * CHUNK);

    float bv = -1.0f;                  // sigmoid outputs are in (0,1)
    unsigned bi = 0u;

#pragma unroll
    for (int i = 0; i < V4_PER_T; ++i) {
        const int e = t + i * NTHREADS;          // coalesced: lane i -> float4 i
        const float4 v = src[e];
        const unsigned idx = base + (unsigned)e * 4u;
        const float s0 = 1.0f / (1.0f + expf(-v.x));
        const float s1 = 1.0f / (1.0f + expf(-v.y));
        const float s2 = 1.0f / (1.0f + expf(-v.z));
        const float s3 = 1.0f / (1.0f + expf(-v.w));
        red(bv, bi, s0, idx);
        red(bv, bi, s1, idx + 1u);
        red(bv, bi, s2, idx + 2u);
        red(bv, bi, s3, idx + 3u);
    }

    // wave64 shuffle reduction
    for (int off = 32; off > 0; off >>= 1) {
        const float    ov = __shfl_down(bv, off, 64);
        const unsigned oi = __shfl_down(bi, off, 64);
        red(bv, bi, ov, oi);
    }

    __shared__ float    sv[NTHREADS / 64];
    __shared__ unsigned si[NTHREADS / 64];
    const int lane = t & 63, wid = t >> 6;
    if (lane == 0) { sv[wid] = bv; si[wid] = bi; }
    __syncthreads();
    if (t == 0) {
        for (int w = 1; w < NTHREADS / 64; ++w) red(bv, bi, sv[w], si[w]);
        pv[b] = bv;
        pi[b] = bi;
    }
}

__global__ __launch_bounds__(64)
void k_phase2(const float* __restrict__ pv, const unsigned* __restrict__ pi,
              float* __restrict__ out) {
    const int k = blockIdx.x;
    const int t = threadIdx.x;

    float bv = -1.0f;
    unsigned bi = 0xFFFFFFFFu;
    if (t < NCHUNK) { bv = pv[k * NCHUNK + t]; bi = pi[k * NCHUNK + t]; }

    for (int off = 32; off > 0; off >>= 1) {
        const float    ov = __shfl_down(bv, off, 64);
        const unsigned oi = __shfl_down(bi, off, 64);
        red(bv, bi, ov, oi);
    }

    if (t == 0) {
        const float conf = bv;
        const bool valid = conf > 0.8f;          // CONF_THRESHOLD
        const float xx = (float)(bi % WW);
        const float yy = (float)(bi / WW);
        const float scale = 4.0f;                // INPUT_SIZE / W = 2048/512
        out[k * 3 + 0] = valid ? xx * scale : -scale;
        out[k * 3 + 1] = valid ? yy * scale : -scale;
        out[k * 3 + 2] = valid ? conf : -1.0f;
    }
}

extern "C" void kernel_launch(void* const* d_in, const int* in_sizes, int n_in,
                              void* d_out, int out_size, void* d_ws, size_t ws_size,
                              hipStream_t stream) {
    const float* x = (const float*)d_in[0];
    float* out = (float*)d_out;

    // workspace: partial (val, idx) per (row, chunk) — 133*16*8 B = 17 KB
    float*    pv = (float*)d_ws;
    unsigned* pi = (unsigned*)((char*)d_ws + (size_t)KPTS * NCHUNK * sizeof(float));

    k_phase1<<<KPTS * NCHUNK, NTHREADS, 0, stream>>>(x, pv, pi);
    k_phase2<<<KPTS, 64, 0, stream>>>(pv, pi, out);
}

// Round 2
// 199.068 us; speedup vs baseline: 1.0617x; 1.0617x over previous
//
#include <hip/hip_runtime.h>
#include <math.h>

// DecodeSBP: x[1,133,512,512] fp32 -> per-keypoint argmax of sigmoid heatmap,
// conf-thresholded joints [133,3] = (x*4, y*4, conf) or (-4,-4,-1).
//
// Key insight: sigmoid is strictly monotone, so argmax(sigmoid(x)) == argmax(x).
// Phase 1 does a raw-x argmax (3 VALU/elem); sigmoid is applied only to the
// 133 winners in phase 2.

#define KPTS     133
#define WW       512
#define HW       (512 * 512)        // 262144 elements per keypoint row
#define NCHUNK   32                 // chunks per row (phase-1 blocks per row)
#define CHUNK    (HW / NCHUNK)      // 8192 elements
#define NTHREADS 256
#define V4_PER_T (CHUNK / 4 / NTHREADS)  // 8 float4 loads per thread

// (val, idx) argmax with first-index tie-break (matches jnp.argmax).
__device__ __forceinline__ void red(float& bv, unsigned& bi, float v, unsigned i) {
    if (v > bv || (v == bv && i < bi)) { bv = v; bi = i; }
}

__global__ __launch_bounds__(NTHREADS)
void k_phase1(const float* __restrict__ x,
              float* __restrict__ pv, unsigned* __restrict__ pi) {
    const int b = blockIdx.x;
    const int k = b / NCHUNK;          // keypoint row
    const int c = b % NCHUNK;          // chunk within row
    const int t = threadIdx.x;

    const float4* src = reinterpret_cast<const float4*>(
        x + (size_t)k * HW + (size_t)c * CHUNK);
    const unsigned base = (unsigned)(c * CHUNK);

    float bv = -3.402823466e+38f;
    unsigned bi = 0u;

#pragma unroll
    for (int i = 0; i < V4_PER_T; ++i) {
        const int e = t + i * NTHREADS;          // coalesced: lane i -> float4 i
        const float4 v = src[e];
        const unsigned idx = base + (unsigned)e * 4u;
        // quad argmax, first-index on ties (>= keeps the earlier element)
        const float    m01 = fmaxf(v.x, v.y);
        const unsigned i01 = (v.x >= v.y) ? idx : idx + 1u;
        const float    m23 = fmaxf(v.z, v.w);
        const unsigned i23 = (v.z >= v.w) ? idx + 2u : idx + 3u;
        const float    m   = fmaxf(m01, m23);
        const unsigned im  = (m01 >= m23) ? i01 : i23;
        // within a thread idx strictly increases, so '>' keeps first index
        if (m > bv) { bv = m; bi = im; }
    }

    // wave64 shuffle reduction (indices interleave across lanes: full tie check)
    for (int off = 32; off > 0; off >>= 1) {
        const float    ov = __shfl_down(bv, off, 64);
        const unsigned oi = __shfl_down(bi, off, 64);
        red(bv, bi, ov, oi);
    }

    __shared__ float    sv[NTHREADS / 64];
    __shared__ unsigned si[NTHREADS / 64];
    const int lane = t & 63, wid = t >> 6;
    if (lane == 0) { sv[wid] = bv; si[wid] = bi; }
    __syncthreads();
    if (t == 0) {
        for (int w = 1; w < NTHREADS / 64; ++w) red(bv, bi, sv[w], si[w]);
        pv[b] = bv;
        pi[b] = bi;
    }
}

__global__ __launch_bounds__(64)
void k_phase2(const float* __restrict__ pv, const unsigned* __restrict__ pi,
              float* __restrict__ out) {
    const int k = blockIdx.x;
    const int t = threadIdx.x;

    float bv = -3.402823466e+38f;
    unsigned bi = 0xFFFFFFFFu;
    if (t < NCHUNK) { bv = pv[k * NCHUNK + t]; bi = pi[k * NCHUNK + t]; }

    for (int off = 32; off > 0; off >>= 1) {
        const float    ov = __shfl_down(bv, off, 64);
        const unsigned oi = __shfl_down(bi, off, 64);
        red(bv, bi, ov, oi);
    }

    if (t == 0) {
        const float conf = 1.0f / (1.0f + expf(-bv));   // sigmoid on winner only
        const bool valid = conf > 0.8f;                 // CONF_THRESHOLD
        const float xx = (float)(bi % WW);
        const float yy = (float)(bi / WW);
        const float scale = 4.0f;                       // INPUT_SIZE / W = 2048/512
        out[k * 3 + 0] = valid ? xx * scale : -scale;
        out[k * 3 + 1] = valid ? yy * scale : -scale;
        out[k * 3 + 2] = valid ? conf : -1.0f;
    }
}

extern "C" void kernel_launch(void* const* d_in, const int* in_sizes, int n_in,
                              void* d_out, int out_size, void* d_ws, size_t ws_size,
                              hipStream_t stream) {
    const float* x = (const float*)d_in[0];
    float* out = (float*)d_out;

    // workspace: partial (val, idx) per (row, chunk) — 133*32*8 B = 34 KB
    float*    pv = (float*)d_ws;
    unsigned* pi = (unsigned*)((char*)d_ws + (size_t)KPTS * NCHUNK * sizeof(float));

    k_phase1<<<KPTS * NCHUNK, NTHREADS, 0, stream>>>(x, pv, pi);
    k_phase2<<<KPTS, 64, 0, stream>>>(pv, pi, out);
}

// Round 4
// 193.969 us; speedup vs baseline: 1.0896x; 1.0263x over previous
//
#include <hip/hip_runtime.h>
#include <math.h>

// DecodeSBP: x[1,133,512,512] fp32 -> per-keypoint argmax of sigmoid heatmap,
// conf-thresholded joints [133,3] = (x*4, y*4, conf) or (-4,-4,-1).
//
// sigmoid is strictly monotone => argmax(sigmoid(x)) == argmax(x).
// Phase 1: raw-x argmax, nontemporal float4 stream (3 VALU/elem).
// Phase 2: reduce 16 partials/row, sigmoid on the 133 winners only.

#define KPTS     133
#define WW       512
#define HW       (512 * 512)        // 262144 elements per keypoint row
#define NCHUNK   16                 // chunks per row (phase-1 blocks per row)
#define CHUNK    (HW / NCHUNK)      // 16384 elements
#define NTHREADS 256
#define V4_PER_T (CHUNK / 4 / NTHREADS)  // 16 float4 loads per thread

// clang native vector — accepted by __builtin_nontemporal_load
// (HIP_vector_type float4 is a struct and is rejected).
typedef float floatx4 __attribute__((ext_vector_type(4)));

// (val, idx) argmax with first-index tie-break (matches jnp.argmax).
__device__ __forceinline__ void red(float& bv, unsigned& bi, float v, unsigned i) {
    if (v > bv || (v == bv && i < bi)) { bv = v; bi = i; }
}

__global__ __launch_bounds__(NTHREADS)
void k_phase1(const float* __restrict__ x,
              float* __restrict__ pv, unsigned* __restrict__ pi) {
    const int b = blockIdx.x;
    const int k = b / NCHUNK;          // keypoint row
    const int c = b % NCHUNK;          // chunk within row
    const int t = threadIdx.x;

    const floatx4* src = reinterpret_cast<const floatx4*>(
        x + (size_t)k * HW + (size_t)c * CHUNK);
    const unsigned base = (unsigned)(c * CHUNK);

    float bv = -3.402823466e+38f;
    unsigned bi = 0u;

    // 16 independent nontemporal float4 loads per thread; compiler stages
    // them in vmcnt batches. Coalesced: wave reads 1 KB/instr.
#pragma unroll
    for (int i = 0; i < V4_PER_T; ++i) {
        const int e = t + i * NTHREADS;
        const floatx4 v = __builtin_nontemporal_load(&src[e]);
        const unsigned idx = base + (unsigned)e * 4u;
        // quad argmax, first-index on ties (>= keeps the earlier element)
        const float    m01 = fmaxf(v.x, v.y);
        const unsigned i01 = (v.x >= v.y) ? idx : idx + 1u;
        const float    m23 = fmaxf(v.z, v.w);
        const unsigned i23 = (v.z >= v.w) ? idx + 2u : idx + 3u;
        const float    m   = fmaxf(m01, m23);
        const unsigned im  = (m01 >= m23) ? i01 : i23;
        // within a thread idx strictly increases, so '>' keeps first index
        if (m > bv) { bv = m; bi = im; }
    }

    // wave64 shuffle reduction (indices interleave across lanes: full tie check)
    for (int off = 32; off > 0; off >>= 1) {
        const float    ov = __shfl_down(bv, off, 64);
        const unsigned oi = __shfl_down(bi, off, 64);
        red(bv, bi, ov, oi);
    }

    __shared__ float    sv[NTHREADS / 64];
    __shared__ unsigned si[NTHREADS / 64];
    const int lane = t & 63, wid = t >> 6;
    if (lane == 0) { sv[wid] = bv; si[wid] = bi; }
    __syncthreads();
    if (t == 0) {
        for (int w = 1; w < NTHREADS / 64; ++w) red(bv, bi, sv[w], si[w]);
        pv[b] = bv;
        pi[b] = bi;
    }
}

__global__ __launch_bounds__(64)
void k_phase2(const float* __restrict__ pv, const unsigned* __restrict__ pi,
              float* __restrict__ out) {
    const int k = blockIdx.x;
    const int t = threadIdx.x;

    float bv = -3.402823466e+38f;
    unsigned bi = 0xFFFFFFFFu;
    if (t < NCHUNK) { bv = pv[k * NCHUNK + t]; bi = pi[k * NCHUNK + t]; }

    for (int off = 32; off > 0; off >>= 1) {
        const float    ov = __shfl_down(bv, off, 64);
        const unsigned oi = __shfl_down(bi, off, 64);
        red(bv, bi, ov, oi);
    }

    if (t == 0) {
        const float conf = 1.0f / (1.0f + expf(-bv));   // sigmoid on winner only
        const bool valid = conf > 0.8f;                 // CONF_THRESHOLD
        const float xx = (float)(bi % WW);
        const float yy = (float)(bi / WW);
        const float scale = 4.0f;                       // INPUT_SIZE / W = 2048/512
        out[k * 3 + 0] = valid ? xx * scale : -scale;
        out[k * 3 + 1] = valid ? yy * scale : -scale;
        out[k * 3 + 2] = valid ? conf : -1.0f;
    }
}

extern "C" void kernel_launch(void* const* d_in, const int* in_sizes, int n_in,
                              void* d_out, int out_size, void* d_ws, size_t ws_size,
                              hipStream_t stream) {
    const float* x = (const float*)d_in[0];
    float* out = (float*)d_out;

    // workspace: partial (val, idx) per (row, chunk) — 133*16*8 B = 17 KB
    float*    pv = (float*)d_ws;
    unsigned* pi = (unsigned*)((char*)d_ws + (size_t)KPTS * NCHUNK * sizeof(float));

    k_phase1<<<KPTS * NCHUNK, NTHREADS, 0, stream>>>(x, pv, pi);
    k_phase2<<<KPTS, 64, 0, stream>>>(pv, pi, out);
}